// Round 3
// baseline (1420.989 us; speedup 1.0000x reference)
//
#include <hip/hip_runtime.h>
#include <math.h>

// Shapes (fixed by the reference): 
// grd_feature: (N=64, C=64, 24, 24)  -> d_in[0]
// sat_feature: (M=64, C=64, 64, 64)  -> d_in[1]
// kH=kW=24, crop sat[:,:,12:52,12:52] (40x40), corr (64,64,17,17)
// out: [0..4096) similarity (M,N) fp32 ; [4096..40960) sat_f (64,24,24) fp32

#define EPSF 1e-12f

// ws layout in floats
#define GRDT_OFF 0u            // 64*64*576 = 2359296 floats: grdT[(c*24+i)*24+j][n]
#define CORR_OFF 2359296u      // 64*64*289 = 1183744 floats (rows y=0..15 valid, p<272)
#define PART_OFF 3543040u      // 64*16*64*17 = 1114112 floats (row 16 partials)
#define IDX_OFF  4657152u      // 4096 ints

// ---------------- K0: transpose grd -> grdT[(c,i,j)][n] ----------------
__global__ __launch_bounds__(256) void grd_transpose(const float* __restrict__ grd,
                                                     float* __restrict__ grdT) {
    __shared__ float tile[64][65];
    int cij0 = blockIdx.x * 64;          // 576 blocks cover 36864 cij
    int tid = threadIdx.x;
#pragma unroll
    for (int k = 0; k < 16; k++) {
        int idx = k * 256 + tid;
        int r = idx >> 6, cc = idx & 63;  // r = n, cc = cij offset
        tile[r][cc] = grd[(size_t)r * 36864 + cij0 + cc];
    }
    __syncthreads();
#pragma unroll
    for (int k = 0; k < 16; k++) {
        int idx = k * 256 + tid;
        int cc = idx >> 6, r = idx & 63;  // write grdT[cij][n]
        grdT[(size_t)(cij0 + cc) * 64 + r] = tile[r][cc];
    }
}

// ---------------- K1: main corr, rows y=0..15 ----------------
// grid 256: bid -> m = bid>>2, ntile = bid&3 (16 n each)
// block 256: tid -> y = tid>>4 (0..15), nl = tid&15
__global__ __launch_bounds__(256) void corr_main(const float* __restrict__ sat,
                                                 const float* __restrict__ grd,
                                                 float* __restrict__ corr) {
    __shared__ __align__(16) float satc[40 * 44];     // stride 44 (conflict avoidance)
    __shared__ __align__(16) float grdL[16 * 580];    // stride 580 (2-way max)

    int bid = blockIdx.x;
    int m  = bid >> 2;
    int n0 = (bid & 3) * 16;
    int tid = threadIdx.x;
    int y  = tid >> 4;     // 0..15
    int nl = tid & 15;     // 0..15

    float acc[17];
#pragma unroll
    for (int x = 0; x < 17; x++) acc[x] = 0.0f;

    const float* satm = sat + (size_t)m * 262144;          // [c][64][64]
    const float* grdn = grd + (size_t)n0 * 36864;          // [t][c][24][24]

    for (int c = 0; c < 64; c++) {
        __syncthreads();
        // stage sat channel: 40 rows x 40 cols (crop starts at (12,12))
        for (int idx = tid; idx < 400; idx += 256) {
            int r = idx / 10, k = idx % 10;
            float4 v = *(const float4*)&satm[(size_t)c * 4096 + (12 + r) * 64 + 12 + 4 * k];
            *(float4*)&satc[r * 44 + 4 * k] = v;
        }
        // stage grd: 16 n x 576
        for (int idx = tid; idx < 2304; idx += 256) {
            int t = idx / 144, w = idx % 144;
            float4 v = *(const float4*)&grdn[(size_t)t * 36864 + c * 576 + 4 * w];
            *(float4*)&grdL[t * 580 + 4 * w] = v;
        }
        __syncthreads();

        for (int i = 0; i < 24; i++) {
            float row[40];
            float g[24];
#pragma unroll
            for (int k = 0; k < 10; k++)
                *(float4*)&row[4 * k] = *(const float4*)&satc[(y + i) * 44 + 4 * k];
#pragma unroll
            for (int k = 0; k < 6; k++)
                *(float4*)&g[4 * k] = *(const float4*)&grdL[nl * 580 + i * 24 + 4 * k];
#pragma unroll
            for (int j = 0; j < 24; j++) {
#pragma unroll
                for (int x = 0; x < 17; x++)
                    acc[x] = fmaf(row[j + x], g[j], acc[x]);
            }
        }
    }

    float* cp = corr + ((size_t)(m * 64 + n0 + nl)) * 289 + y * 17;
#pragma unroll
    for (int x = 0; x < 17; x++) cp[x] = acc[x];
}

// ---------------- K2: tail corr, row y=16 (partials over 16 channel-groups) ----
// grid 1024: bid -> m = bid>>4, cg = bid&15 (4 channels each); block 64: lane = n
__global__ __launch_bounds__(64) void corr_tail(const float* __restrict__ sat,
                                                const float* __restrict__ grdT,
                                                float* __restrict__ part) {
    int bid = blockIdx.x;
    int m  = bid >> 4;
    int cg = bid & 15;
    int n  = threadIdx.x;

    float acc[17];
#pragma unroll
    for (int x = 0; x < 17; x++) acc[x] = 0.0f;

    for (int cc = 0; cc < 4; cc++) {
        int c = cg * 4 + cc;
        const float* satc = sat + (size_t)(m * 64 + c) * 4096;
        for (int i = 0; i < 24; i++) {
            // uniform row: crop row 16+i -> absolute row 28+i, cols 12..51
            const float* rp = satc + (28 + i) * 64 + 12;
            float row[40];
#pragma unroll
            for (int k = 0; k < 10; k++) {
                float4 v = *(const float4*)&rp[4 * k];
                row[4 * k + 0] = v.x; row[4 * k + 1] = v.y;
                row[4 * k + 2] = v.z; row[4 * k + 3] = v.w;
            }
#pragma unroll
            for (int j = 0; j < 24; j++) {
                float gv = grdT[(size_t)((c * 24 + i) * 24 + j) * 64 + n];
#pragma unroll
                for (int x = 0; x < 17; x++)
                    acc[x] = fmaf(row[j + x], gv, acc[x]);
            }
        }
    }

    float* pp = part + ((size_t)bid * 64 + n) * 17;
#pragma unroll
    for (int x = 0; x < 17; x++) pp[x] = acc[x];
}

// ---------------- K3: argmax over 289 positions ----------------
// grid 4096 (b = m*64+n), block 64
__global__ __launch_bounds__(64) void argmax_k(const float* __restrict__ corr,
                                               const float* __restrict__ part,
                                               int* __restrict__ idxout) {
    int b = blockIdx.x;
    int m = b >> 6, n = b & 63;
    int lane = threadIdx.x;

    float bv = -3.0e38f;
    int bi = 1 << 30;

    const float* cp = corr + (size_t)b * 289;
    for (int p = lane; p < 272; p += 64) {
        float v = cp[p];
        if (v > bv) { bv = v; bi = p; }   // ascending p -> strict > keeps first occurrence
    }
    if (lane < 17) {
        float v = 0.0f;
        for (int cg = 0; cg < 16; cg++)
            v += part[((size_t)(m * 16 + cg) * 64 + n) * 17 + lane];
        int p = 272 + lane;
        if (v > bv) { bv = v; bi = p; }
    }
    for (int off = 32; off; off >>= 1) {
        float ov = __shfl_down(bv, off);
        int   oi = __shfl_down(bi, off);
        if (ov > bv || (ov == bv && oi < bi)) { bv = ov; bi = oi; }
    }
    if (lane == 0) idxout[b] = bi;
}

// ---------------- K4: exact similarity at argmax ----------------
// grid 4096 (b = m*64+n), block 256
__global__ __launch_bounds__(256) void sim_k(const float* __restrict__ sat,
                                             const float* __restrict__ grd,
                                             const int* __restrict__ idxbuf,
                                             float* __restrict__ out) {
    int b = blockIdx.x;
    int m = b >> 6, n = b & 63;
    int fidx = idxbuf[b];
    int hy = fidx / 17, wx = fidx % 17;
    int tid = threadIdx.x;

    float dot = 0.0f, pp = 0.0f, gg = 0.0f;
    const float* satm = sat + (size_t)m * 262144;
    const float* grdn = grd + (size_t)n * 36864;

    for (int c = 0; c < 64; c++) {
        const float* sc = satm + (size_t)c * 4096;
        const float* gc = grdn + (size_t)c * 576;
        for (int e = tid; e < 576; e += 256) {
            int r = e / 24, col = e - r * 24;
            float p = sc[(12 + hy + r) * 64 + 12 + wx + col];
            float g = gc[e];
            dot += p * g;
            pp  += p * p;
            gg  += g * g;
        }
    }

    // block reduce (4 waves)
    for (int off = 32; off; off >>= 1) {
        dot += __shfl_down(dot, off);
        pp  += __shfl_down(pp, off);
        gg  += __shfl_down(gg, off);
    }
    __shared__ float red[3][4];
    int wid = tid >> 6, lane = tid & 63;
    if (lane == 0) { red[0][wid] = dot; red[1][wid] = pp; red[2][wid] = gg; }
    __syncthreads();
    if (tid == 0) {
        float d = 0, P = 0, G = 0;
        for (int w = 0; w < 4; w++) { d += red[0][w]; P += red[1][w]; G += red[2][w]; }
        out[b] = d / (fmaxf(sqrtf(P), EPSF) * fmaxf(sqrtf(G), EPSF));
    }
}

// ---------------- K5: copy winning patch for (m,n)=(63,63) ----------------
// grid 144, block 256
__global__ __launch_bounds__(256) void copy_patch(const float* __restrict__ sat,
                                                  const int* __restrict__ idxbuf,
                                                  float* __restrict__ out) {
    int fidx = idxbuf[4095];
    int hy = fidx / 17, wx = fidx % 17;
    int e = blockIdx.x * 256 + threadIdx.x;   // < 36864
    int c = e / 576;
    int rem = e - c * 576;
    int r = rem / 24, col = rem - r * 24;
    out[4096 + e] = sat[(size_t)(63 * 64 + c) * 4096 + (12 + hy + r) * 64 + 12 + wx + col];
}

extern "C" void kernel_launch(void* const* d_in, const int* in_sizes, int n_in,
                              void* d_out, int out_size, void* d_ws, size_t ws_size,
                              hipStream_t stream) {
    const float* grd = (const float*)d_in[0];   // (64,64,24,24)
    const float* sat = (const float*)d_in[1];   // (64,64,64,64)
    float* out = (float*)d_out;

    float* wsf  = (float*)d_ws;
    float* grdT = wsf + GRDT_OFF;
    float* corr = wsf + CORR_OFF;
    float* part = wsf + PART_OFF;
    int*   idxb = (int*)(wsf + IDX_OFF);

    grd_transpose<<<576, 256, 0, stream>>>(grd, grdT);
    corr_main<<<256, 256, 0, stream>>>(sat, grd, corr);
    corr_tail<<<1024, 64, 0, stream>>>(sat, grdT, part);
    argmax_k<<<4096, 64, 0, stream>>>(corr, part, idxb);
    sim_k<<<4096, 256, 0, stream>>>(sat, grd, idxb, out);
    copy_patch<<<144, 256, 0, stream>>>(sat, idxb, out);
}